// Round 5
// baseline (176.485 us; speedup 1.0000x reference)
//
#include <hip/hip_runtime.h>
#include <hip/hip_bf16.h>

// ---- problem constants ----
#define HID   1024
#define NEXP  8
#define NPAIR 4096                       // TOKENS * TOPK
#define BMPAD 128                        // segment padding = BM
#define PERM_MAX (NPAIR + NEXP * BMPAD)  // 5120
#define MT_MAX (PERM_MAX / 128)          // 40 M-tiles

typedef unsigned short u16;
typedef __attribute__((ext_vector_type(8))) short bf16x8;
typedef __attribute__((ext_vector_type(4))) float f32x4;
typedef __attribute__((ext_vector_type(4))) unsigned short us4;

static __device__ __forceinline__ u16 f2bf(float f) {
  union { float f; unsigned u; } v; v.f = f;
  unsigned u = v.u;
  unsigned r = (u + 0x7fffu + ((u >> 16) & 1u)) >> 16;
  return (u16)r;
}

// pack 2 f32 -> 2 bf16 (v_cvt_pk_bf16_f32)
static __device__ __forceinline__ unsigned pk2(float a, float b) {
  __hip_bfloat162 h = __float22bfloat162_rn(make_float2(a, b));
  union { __hip_bfloat162 h; unsigned u; } c; c.h = h; return c.u;
}

// 8 f32 -> bf16x8 fragment
static __device__ __forceinline__ bf16x8 cvt8(f32x4 a, f32x4 b) {
  union { unsigned u[4]; bf16x8 v; } r;
  r.u[0] = pk2(a[0], a[1]); r.u[1] = pk2(a[2], a[3]);
  r.u[2] = pk2(b[0], b[1]); r.u[3] = pk2(b[2], b[3]);
  return r.v;
}

static __device__ __forceinline__ void gload16(const void* g, void* l) {
  __builtin_amdgcn_global_load_lds(
      (const __attribute__((address_space(1))) unsigned int*)g,
      (__attribute__((address_space(3))) unsigned int*)l, 16, 0, 0);
}

static __device__ __forceinline__ f32x4 mfma_bf16(bf16x8 a, bf16x8 b, f32x4 c) {
  return __builtin_amdgcn_mfma_f32_16x16x32_bf16(a, b, c, 0, 0, 0);
}

// ---- prep: zero d_out, convert x -> bf16 ----
__global__ __launch_bounds__(256) void k_prep(const float* __restrict__ x,
                                              u16* __restrict__ xb,
                                              float* __restrict__ out) {
  int i = blockIdx.x * 256 + threadIdx.x;
  int base = i * 8;
  f32x4 v0 = *(const f32x4*)(x + base);
  f32x4 v1 = *(const f32x4*)(x + base + 4);
  us4 a = { f2bf(v0[0]), f2bf(v0[1]), f2bf(v0[2]), f2bf(v0[3]) };
  us4 b = { f2bf(v1[0]), f2bf(v1[1]), f2bf(v1[2]), f2bf(v1[3]) };
  *(us4*)(xb + base)     = a;
  *(us4*)(xb + base + 4) = b;
  f32x4 z = {0.f, 0.f, 0.f, 0.f};
  *(f32x4*)(out + base)     = z;
  *(f32x4*)(out + base + 4) = z;
}

// ---- routing ----
__global__ __launch_bounds__(256) void k_route(const int* __restrict__ sel,
                                               int* __restrict__ hdr,
                                               int* __restrict__ perm) {
  __shared__ int cnt[NEXP];
  __shared__ int cur[NEXP];
  int tid = threadIdx.x;
  if (tid < NEXP) cnt[tid] = 0;
  __syncthreads();
  for (int p = tid; p < NPAIR; p += 256) atomicAdd(&cnt[sel[p]], 1);
  __syncthreads();
  if (tid == 0) {
    int acc = 0;
    for (int e = 0; e < NEXP; e++) {
      hdr[e] = acc;
      cur[e] = acc;
      acc += (cnt[e] + 127) & ~127;
    }
    hdr[NEXP] = acc;
  }
  __syncthreads();
  for (int i = tid; i < PERM_MAX; i += 256) perm[i] = -1;
  __syncthreads();
  for (int p = tid; p < NPAIR; p += 256) {
    int e = sel[p];
    int slot = atomicAdd(&cur[e], 1);
    perm[slot] = p;
  }
}

// ==== GEMM 1: gate+up fused, SwiGLU -> hbuf ====
// BM=128, BN=64 per matrix, BK=64. 8 waves (2M x 4N); wave = 64 rows x 16 cols
// of each matrix (M-rep 4). A in LDS via global_load_lds (2-buf, counted vmcnt,
// raw barrier). B f32 per-lane from global, cvt_pk -> bf16 in regs.
__global__ __launch_bounds__(512, 4) void k_gateup(const u16* __restrict__ xb,
                                                   const float* __restrict__ gw,
                                                   const float* __restrict__ uw,
                                                   const int* __restrict__ hdr,
                                                   const int* __restrict__ perm,
                                                   u16* __restrict__ hbuf) {
  __shared__ __align__(16) u16 lA[2][128 * 64];   // 2 x 16 KB

  const int tid = threadIdx.x, lane = tid & 63, wv = tid >> 6;
  // XCD swizzle: consecutive M-tiles of same (e, nt) land on the same XCD.
  const int wgid = blockIdx.x;
  const int slot = wgid >> 3;
  const int nt = ((slot & 1) << 3) | (wgid & 7);
  const int mt = slot >> 1;
  const int n0 = nt * 64, m0 = mt * 128;
  if (m0 >= hdr[NEXP]) return;
  int e = 0;
  #pragma unroll
  for (int k = 1; k < NEXP; k++) if (m0 >= hdr[k]) e = k;

  // A staging: 1024 chunks of 16B; thread does 2 (tid, tid+512).
  const u16* srcA[2]; int dstAo[2];
  #pragma unroll
  for (int j = 0; j < 2; j++) {
    int c = tid + 512 * j;
    int r = c >> 3, q = c & 7;
    int p = perm[m0 + r];
    int tok = (p < 0) ? 0 : (p >> 1);
    int sw = q ^ (r & 7);
    srcA[j] = xb + (size_t)tok * HID + sw * 8;
    dstAo[j] = r * 64 + q * 8;
  }

  const int wm = wv >> 2, wn = wv & 3;
  const int fr = lane & 15, fq = lane >> 4;
  const size_t eb = (size_t)e * (1 << 20);
  const int brow = n0 + wn * 16 + fr;
  const float* pG = gw + eb + (size_t)brow * HID + fq * 8;
  const float* pU = uw + eb + (size_t)brow * HID + fq * 8;

  f32x4 ng[2][2], nu[2][2];   // f32 stage regs (single-buffered)
  bf16x8 fg[2], fu[2];        // converted fragments
  f32x4 ag[4], au[4];
  #pragma unroll
  for (int i = 0; i < 4; i++) {
    ag[i] = (f32x4){0.f, 0.f, 0.f, 0.f};
    au[i] = (f32x4){0.f, 0.f, 0.f, 0.f};
  }

#define GU_GLA(B, K0) {                                                        \
    _Pragma("unroll") for (int j = 0; j < 2; j++)                              \
      gload16(srcA[j] + (K0), &lA[B][dstAo[j]]); }

#define GU_LOADB(K0) {                                                         \
    _Pragma("unroll") for (int kk2 = 0; kk2 < 2; kk2++) {                      \
      ng[kk2][0] = *(const f32x4*)(pG + (K0) + kk2 * 32);                      \
      ng[kk2][1] = *(const f32x4*)(pG + (K0) + kk2 * 32 + 4);                  \
      nu[kk2][0] = *(const f32x4*)(pU + (K0) + kk2 * 32);                      \
      nu[kk2][1] = *(const f32x4*)(pU + (K0) + kk2 * 32 + 4);                  \
    } }

#define GU_CVTB() {                                                            \
    fg[0] = cvt8(ng[0][0], ng[0][1]); fg[1] = cvt8(ng[1][0], ng[1][1]);        \
    fu[0] = cvt8(nu[0][0], nu[0][1]); fu[1] = cvt8(nu[1][0], nu[1][1]); }

#define GU_COMP(B) {                                                           \
    _Pragma("unroll") for (int kk2 = 0; kk2 < 2; kk2++) {                      \
      _Pragma("unroll") for (int m2 = 0; m2 < 4; m2++) {                       \
        int r = wm * 64 + m2 * 16 + fr, q = kk2 * 4 + fq;                      \
        bf16x8 af = *(const bf16x8*)&lA[B][r * 64 + (q ^ (r & 7)) * 8];        \
        ag[m2] = mfma_bf16(af, fg[kk2], ag[m2]);                               \
        au[m2] = mfma_bf16(af, fu[kk2], au[m2]);                               \
      }                                                                        \
    } }

  // prologue: stage(0) in flight
  GU_GLA(0, 0);
  GU_LOADB(0);
  for (int t = 0; t < 16; ++t) {
    const int c = t & 1;
    // retire my stage(t) gload_lds (8 newer B loads allowed in flight);
    // barrier => all waves' stage(t) landed AND everyone done reading buf c^1.
    asm volatile("s_waitcnt vmcnt(8)" ::: "memory");
    __builtin_amdgcn_s_barrier();
    __builtin_amdgcn_sched_barrier(0);
    GU_CVTB();                                  // consume B(t) (compiler waits)
    if (t < 15) { GU_GLA(c ^ 1, (t + 1) * 64); GU_LOADB((t + 1) * 64); }
    GU_COMP(c);                                 // MFMA over ~10 in-flight loads
  }
#undef GU_GLA
#undef GU_LOADB
#undef GU_CVTB
#undef GU_COMP

  // epilogue: h = silu(g) * u -> bf16
  #pragma unroll
  for (int m2 = 0; m2 < 4; m2++)
    #pragma unroll
    for (int q = 0; q < 4; q++) {
      int row = m0 + wm * 64 + m2 * 16 + fq * 4 + q;
      int col = n0 + wn * 16 + fr;
      float g = ag[m2][q];
      float u = au[m2][q];
      float h = (g / (1.0f + __expf(-g))) * u;
      hbuf[(size_t)row * HID + col] = f2bf(h);
    }
}

// ==== GEMM 2: down, weighted atomic scatter ====
// BM=128, BN=64, BK=64. 8 waves (2M x 4N); wave = 64 rows x 16 cols.
__global__ __launch_bounds__(512, 4) void k_down(const u16* __restrict__ hbuf,
                                                 const float* __restrict__ dw,
                                                 const int* __restrict__ hdr,
                                                 const int* __restrict__ perm,
                                                 const float* __restrict__ rw,
                                                 float* __restrict__ out) {
  __shared__ __align__(16) u16 lA[2][128 * 64];   // 2 x 16 KB

  const int tid = threadIdx.x, lane = tid & 63, wv = tid >> 6;
  const int wgid = blockIdx.x;
  const int slot = wgid >> 3;
  const int nt = ((slot & 1) << 3) | (wgid & 7);
  const int mt = slot >> 1;
  const int n0 = nt * 64, m0 = mt * 128;
  if (m0 >= hdr[NEXP]) return;
  int e = 0;
  #pragma unroll
  for (int k = 1; k < NEXP; k++) if (m0 >= hdr[k]) e = k;

  const u16* srcA[2]; int dstAo[2];
  #pragma unroll
  for (int j = 0; j < 2; j++) {
    int c = tid + 512 * j;
    int r = c >> 3, q = c & 7;
    int sw = q ^ (r & 7);
    srcA[j] = hbuf + (size_t)(m0 + r) * HID + sw * 8;
    dstAo[j] = r * 64 + q * 8;
  }

  const int wm = wv >> 2, wn = wv & 3;
  const int fr = lane & 15, fq = lane >> 4;
  const size_t eb = (size_t)e * (1 << 20);
  const int brow = n0 + wn * 16 + fr;
  const float* pB = dw + eb + (size_t)brow * HID + fq * 8;

  f32x4 nb[2][2];
  bf16x8 fb[2];
  f32x4 acc[4];
  #pragma unroll
  for (int i = 0; i < 4; i++) acc[i] = (f32x4){0.f, 0.f, 0.f, 0.f};

#define DN_GLA(B, K0) {                                                        \
    _Pragma("unroll") for (int j = 0; j < 2; j++)                              \
      gload16(srcA[j] + (K0), &lA[B][dstAo[j]]); }

#define DN_LOADB(K0) {                                                         \
    _Pragma("unroll") for (int kk2 = 0; kk2 < 2; kk2++) {                      \
      nb[kk2][0] = *(const f32x4*)(pB + (K0) + kk2 * 32);                      \
      nb[kk2][1] = *(const f32x4*)(pB + (K0) + kk2 * 32 + 4);                  \
    } }

#define DN_CVTB() {                                                            \
    fb[0] = cvt8(nb[0][0], nb[0][1]); fb[1] = cvt8(nb[1][0], nb[1][1]); }

#define DN_COMP(B) {                                                           \
    _Pragma("unroll") for (int kk2 = 0; kk2 < 2; kk2++) {                      \
      _Pragma("unroll") for (int m2 = 0; m2 < 4; m2++) {                       \
        int r = wm * 64 + m2 * 16 + fr, q = kk2 * 4 + fq;                      \
        bf16x8 af = *(const bf16x8*)&lA[B][r * 64 + (q ^ (r & 7)) * 8];        \
        acc[m2] = mfma_bf16(af, fb[kk2], acc[m2]);                             \
      }                                                                        \
    } }

  DN_GLA(0, 0);
  DN_LOADB(0);
  for (int t = 0; t < 16; ++t) {
    const int c = t & 1;
    asm volatile("s_waitcnt vmcnt(4)" ::: "memory");
    __builtin_amdgcn_s_barrier();
    __builtin_amdgcn_sched_barrier(0);
    DN_CVTB();
    if (t < 15) { DN_GLA(c ^ 1, (t + 1) * 64); DN_LOADB((t + 1) * 64); }
    DN_COMP(c);
  }
#undef DN_GLA
#undef DN_LOADB
#undef DN_CVTB
#undef DN_COMP

  // epilogue: out[token] += w * val
  #pragma unroll
  for (int m2 = 0; m2 < 4; m2++)
    #pragma unroll
    for (int q = 0; q < 4; q++) {
      int row = m0 + wm * 64 + m2 * 16 + fq * 4 + q;
      int p = perm[row];
      if (p < 0) continue;
      int t = p >> 1;
      float w = rw[p];
      int col = n0 + wn * 16 + fr;
      atomicAdd(&out[(size_t)t * HID + col], acc[m2][q] * w);
    }
}

extern "C" void kernel_launch(void* const* d_in, const int* in_sizes, int n_in,
                              void* d_out, int out_size, void* d_ws, size_t ws_size,
                              hipStream_t stream) {
  const float* x   = (const float*)d_in[0];
  const float* rw  = (const float*)d_in[1];
  const int*   sel = (const int*)d_in[2];
  const float* gw  = (const float*)d_in[4];
  const float* uw  = (const float*)d_in[5];
  const float* dw  = (const float*)d_in[6];
  float* out = (float*)d_out;

  char* ws = (char*)d_ws;
  int*  hdr  = (int*)ws;                          // seg_base[9]
  int*  perm = (int*)(ws + 1024);                 // PERM_MAX ints
  u16*  xb   = (u16*)(ws + (1 << 16));            // 2M bf16 = 4 MiB
  u16*  hbuf = xb + (2 << 20);                    // 5120*1024 bf16 = 10 MiB

  k_prep <<<dim3(1024), dim3(256), 0, stream>>>(x, xb, out);
  k_route<<<dim3(1),    dim3(256), 0, stream>>>(sel, hdr, perm);
  k_gateup<<<dim3(16 * MT_MAX), dim3(512), 0, stream>>>(xb, gw, uw, hdr, perm, hbuf);
  k_down  <<<dim3(16 * MT_MAX), dim3(512), 0, stream>>>(hbuf, dw, hdr, perm, rw, out);
}

// Round 6
// 111.618 us; speedup vs baseline: 1.5811x; 1.5811x over previous
//
#include <hip/hip_runtime.h>
#include <hip/hip_bf16.h>

// ---- problem constants ----
#define HID   1024
#define NEXP  8
#define NPAIR 4096                       // TOKENS * TOPK
#define BMPAD 128                        // segment padding = BM
#define PERM_MAX (NPAIR + NEXP * BMPAD)  // 5120
#define MT_MAX (PERM_MAX / 128)          // 40 M-tiles

typedef unsigned short u16;
typedef __attribute__((ext_vector_type(8))) short bf16x8;
typedef __attribute__((ext_vector_type(4))) float f32x4;
typedef __attribute__((ext_vector_type(4))) unsigned short us4;
typedef __attribute__((ext_vector_type(4))) unsigned int u32x4;

// raw barrier: LDS drained, but vmcnt NOT drained (prefetches stay in flight)
#define BAR() asm volatile("s_waitcnt lgkmcnt(0)\ns_barrier" ::: "memory")

static __device__ __forceinline__ u16 f2bf(float f) {
  union { float f; unsigned u; } v; v.f = f;
  unsigned u = v.u;
  unsigned r = (u + 0x7fffu + ((u >> 16) & 1u)) >> 16;
  return (u16)r;
}

// pack 2 f32 -> 2 bf16 (v_cvt_pk_bf16_f32)
static __device__ __forceinline__ unsigned pk2(float a, float b) {
  __hip_bfloat162 h = __float22bfloat162_rn(make_float2(a, b));
  union { __hip_bfloat162 h; unsigned u; } c; c.h = h; return c.u;
}

static __device__ __forceinline__ void gload16(const void* g, void* l) {
  __builtin_amdgcn_global_load_lds(
      (const __attribute__((address_space(1))) unsigned int*)g,
      (__attribute__((address_space(3))) unsigned int*)l, 16, 0, 0);
}

static __device__ __forceinline__ f32x4 mfma_bf16(bf16x8 a, bf16x8 b, f32x4 c) {
  return __builtin_amdgcn_mfma_f32_16x16x32_bf16(a, b, c, 0, 0, 0);
}

// ---- prep: zero d_out, convert x -> bf16 ----
__global__ __launch_bounds__(256) void k_prep(const float* __restrict__ x,
                                              u16* __restrict__ xb,
                                              float* __restrict__ out) {
  int i = blockIdx.x * 256 + threadIdx.x;
  int base = i * 8;
  f32x4 v0 = *(const f32x4*)(x + base);
  f32x4 v1 = *(const f32x4*)(x + base + 4);
  us4 a = { f2bf(v0[0]), f2bf(v0[1]), f2bf(v0[2]), f2bf(v0[3]) };
  us4 b = { f2bf(v1[0]), f2bf(v1[1]), f2bf(v1[2]), f2bf(v1[3]) };
  *(us4*)(xb + base)     = a;
  *(us4*)(xb + base + 4) = b;
  f32x4 z = {0.f, 0.f, 0.f, 0.f};
  *(f32x4*)(out + base)     = z;
  *(f32x4*)(out + base + 4) = z;
}

// ---- routing ----
__global__ __launch_bounds__(256) void k_route(const int* __restrict__ sel,
                                               int* __restrict__ hdr,
                                               int* __restrict__ perm) {
  __shared__ int cnt[NEXP];
  __shared__ int cur[NEXP];
  int tid = threadIdx.x;
  if (tid < NEXP) cnt[tid] = 0;
  __syncthreads();
  for (int p = tid; p < NPAIR; p += 256) atomicAdd(&cnt[sel[p]], 1);
  __syncthreads();
  if (tid == 0) {
    int acc = 0;
    for (int e = 0; e < NEXP; e++) {
      hdr[e] = acc;
      cur[e] = acc;
      acc += (cnt[e] + 127) & ~127;
    }
    hdr[NEXP] = acc;
  }
  __syncthreads();
  for (int i = tid; i < PERM_MAX; i += 256) perm[i] = -1;
  __syncthreads();
  for (int p = tid; p < NPAIR; p += 256) {
    int e = sel[p];
    int slot = atomicAdd(&cur[e], 1);
    perm[slot] = p;
  }
}

// ==== GEMM 1: gate+up fused, SwiGLU -> hbuf (bf16) ====
// BM=128, BN=64/matrix, BK=64; 4 waves 2x2 (per wave 64x32 per matrix).
// A: bf16, double-buffered LDS via global_load_lds (linear dest, pre-swizzled src).
// B: f32 reg-prefetched 1 K-step ahead (coalesced), cvt_pk -> bf16, ds_write.
// Raw barriers so the in-flight prefetches cross them undrained.
__global__ __launch_bounds__(256) void k_gateup(const u16* __restrict__ xb,
                                                const float* __restrict__ gw,
                                                const float* __restrict__ uw,
                                                const int* __restrict__ hdr,
                                                const int* __restrict__ perm,
                                                u16* __restrict__ hbuf) {
  __shared__ __align__(16) u16 lA[2][128 * 64];   // 32 KB
  __shared__ __align__(16) u16 lBg[64 * 64];      //  8 KB
  __shared__ __align__(16) u16 lBu[64 * 64];      //  8 KB  (48 KB total -> 3 blk/CU)

  const int tid = threadIdx.x, lane = tid & 63, wv = tid >> 6;
  const int n0 = blockIdx.x * 64, m0 = blockIdx.y * 128;
  if (m0 >= hdr[NEXP]) return;
  int e = 0;
  #pragma unroll
  for (int k = 1; k < NEXP; k++) if (m0 >= hdr[k]) e = k;

  // A staging: 16 x 1KiB wave-issues (4/thread). LDS linear; src pre-swizzled.
  const u16* srcA[4]; int dstAo[4];
  #pragma unroll
  for (int j = 0; j < 4; j++) {
    int rt = wv * 32 + j * 8 + (lane >> 3);
    int p = perm[m0 + rt];
    int tok = (p < 0) ? 0 : (p >> 1);
    int sw = (lane & 7) ^ (rt & 7);
    srcA[j] = xb + (size_t)tok * HID + sw * 8;
    dstAo[j] = (wv * 32 + j * 8) * 64;
  }
  // B staging (f32, coalesced): thread owns row br, 16 consecutive floats at cb.
  const int br = wv * 16 + (lane >> 2);
  const int cb = (lane & 3) * 16;
  const size_t eb = (size_t)e * (1 << 20);
  const float* pG = gw + eb + (size_t)(n0 + br) * HID + cb;
  const float* pU = uw + eb + (size_t)(n0 + br) * HID + cb;
  const int bws0 = br * 64 + ((((lane & 3) * 2 + 0) ^ (br & 7)) * 8);
  const int bws1 = br * 64 + ((((lane & 3) * 2 + 1) ^ (br & 7)) * 8);

  const int wm = wv >> 1, wn = wv & 1;
  const int fr = lane & 15, fq = lane >> 4;

  f32x4 vg[4], vu[4];           // B f32 stage regs (1 step ahead)
  f32x4 accg[4][2], accu[4][2];
  #pragma unroll
  for (int a = 0; a < 4; a++)
    #pragma unroll
    for (int b = 0; b < 2; b++) {
      accg[a][b] = (f32x4){0.f, 0.f, 0.f, 0.f};
      accu[a][b] = (f32x4){0.f, 0.f, 0.f, 0.f};
    }

#define GU_GLA(B, K0) {                                                        \
    _Pragma("unroll") for (int j = 0; j < 4; j++)                              \
      gload16(srcA[j] + (K0), &lA[B][dstAo[j]]); }

#define GU_LOADB(K0) {                                                         \
    _Pragma("unroll") for (int i = 0; i < 4; i++) {                            \
      vg[i] = *(const f32x4*)(pG + (K0) + i * 4);                              \
      vu[i] = *(const f32x4*)(pU + (K0) + i * 4);                              \
    } }

#define GU_CVTW() {                                                            \
    u32x4 w0 = { pk2(vg[0][0], vg[0][1]), pk2(vg[0][2], vg[0][3]),             \
                 pk2(vg[1][0], vg[1][1]), pk2(vg[1][2], vg[1][3]) };           \
    *(u32x4*)&lBg[bws0] = w0;                                                  \
    u32x4 w1 = { pk2(vg[2][0], vg[2][1]), pk2(vg[2][2], vg[2][3]),             \
                 pk2(vg[3][0], vg[3][1]), pk2(vg[3][2], vg[3][3]) };           \
    *(u32x4*)&lBg[bws1] = w1;                                                  \
    u32x4 w2 = { pk2(vu[0][0], vu[0][1]), pk2(vu[0][2], vu[0][3]),             \
                 pk2(vu[1][0], vu[1][1]), pk2(vu[1][2], vu[1][3]) };           \
    *(u32x4*)&lBu[bws0] = w2;                                                  \
    u32x4 w3 = { pk2(vu[2][0], vu[2][1]), pk2(vu[2][2], vu[2][3]),             \
                 pk2(vu[3][0], vu[3][1]), pk2(vu[3][2], vu[3][3]) };           \
    *(u32x4*)&lBu[bws1] = w3; }

#define GU_COMP(B) {                                                           \
    _Pragma("unroll") for (int kk2 = 0; kk2 < 2; kk2++) {                      \
      bf16x8 af[4], bg[2], bu[2];                                              \
      _Pragma("unroll") for (int m2 = 0; m2 < 4; m2++) {                       \
        int r = wm * 64 + m2 * 16 + fr, q = kk2 * 4 + fq;                      \
        af[m2] = *(const bf16x8*)&lA[B][r * 64 + (q ^ (r & 7)) * 8];           \
      }                                                                        \
      _Pragma("unroll") for (int n2 = 0; n2 < 2; n2++) {                       \
        int r = wn * 32 + n2 * 16 + fr, q = kk2 * 4 + fq;                      \
        bg[n2] = *(const bf16x8*)&lBg[r * 64 + (q ^ (r & 7)) * 8];             \
        bu[n2] = *(const bf16x8*)&lBu[r * 64 + (q ^ (r & 7)) * 8];             \
      }                                                                        \
      _Pragma("unroll") for (int m2 = 0; m2 < 4; m2++)                         \
        _Pragma("unroll") for (int n2 = 0; n2 < 2; n2++) {                     \
          accg[m2][n2] = mfma_bf16(af[m2], bg[n2], accg[m2][n2]);              \
          accu[m2][n2] = mfma_bf16(af[m2], bu[n2], accu[m2][n2]);              \
        }                                                                      \
    } }

  // prologue: A(0) + B(0) in flight
  GU_GLA(0, 0);
  GU_LOADB(0);
  for (int t = 0; t < 16; ++t) {
    const int c = t & 1;
    // ds_write B(t): compiler drains vmcnt here (loads had a full iter of cover);
    // this also retires A(t)'s global_load_lds into lA[c].
    GU_CVTW();
    if (t < 15) {
      GU_GLA(c ^ 1, (t + 1) * 64);   // prefetch A(t+1) -> other buffer
      GU_LOADB((t + 1) * 64);        // prefetch B(t+1) -> regs
    }
    BAR();                           // barrier1: LDS writes visible; prefetches stay in flight
    GU_COMP(c);
    BAR();                           // barrier2: LDS reads done before next overwrite
  }
#undef GU_GLA
#undef GU_LOADB
#undef GU_CVTW
#undef GU_COMP

  // epilogue: h = silu(g) * u -> bf16
  #pragma unroll
  for (int m2 = 0; m2 < 4; m2++)
    #pragma unroll
    for (int n2 = 0; n2 < 2; n2++)
      #pragma unroll
      for (int q = 0; q < 4; q++) {
        int row = m0 + wm * 64 + m2 * 16 + fq * 4 + q;
        int col = n0 + wn * 32 + n2 * 16 + fr;
        float g = accg[m2][n2][q];
        float u = accu[m2][n2][q];
        float h = (g / (1.0f + __expf(-g))) * u;
        hbuf[(size_t)row * HID + col] = f2bf(h);
      }
}

// ==== GEMM 2: down, weighted atomic scatter ====
// Same skeleton; single B matrix (40 KB LDS -> 4 blk/CU).
__global__ __launch_bounds__(256) void k_down(const u16* __restrict__ hbuf,
                                              const float* __restrict__ dw,
                                              const int* __restrict__ hdr,
                                              const int* __restrict__ perm,
                                              const float* __restrict__ rw,
                                              float* __restrict__ out) {
  __shared__ __align__(16) u16 lA[2][128 * 64];   // 32 KB
  __shared__ __align__(16) u16 lB[64 * 64];       //  8 KB

  const int tid = threadIdx.x, lane = tid & 63, wv = tid >> 6;
  const int n0 = blockIdx.x * 64, m0 = blockIdx.y * 128;
  if (m0 >= hdr[NEXP]) return;
  int e = 0;
  #pragma unroll
  for (int k = 1; k < NEXP; k++) if (m0 >= hdr[k]) e = k;

  const u16* srcA[4]; int dstAo[4];
  #pragma unroll
  for (int j = 0; j < 4; j++) {
    int rt = wv * 32 + j * 8 + (lane >> 3);
    int sw = (lane & 7) ^ (rt & 7);
    srcA[j] = hbuf + (size_t)(m0 + rt) * HID + sw * 8;
    dstAo[j] = (wv * 32 + j * 8) * 64;
  }
  const int br = wv * 16 + (lane >> 2);
  const int cb = (lane & 3) * 16;
  const size_t eb = (size_t)e * (1 << 20);
  const float* pB = dw + eb + (size_t)(n0 + br) * HID + cb;
  const int bws0 = br * 64 + ((((lane & 3) * 2 + 0) ^ (br & 7)) * 8);
  const int bws1 = br * 64 + ((((lane & 3) * 2 + 1) ^ (br & 7)) * 8);

  const int wm = wv >> 1, wn = wv & 1;
  const int fr = lane & 15, fq = lane >> 4;

  f32x4 vb[4];
  f32x4 acc[4][2];
  #pragma unroll
  for (int a = 0; a < 4; a++)
    #pragma unroll
    for (int b = 0; b < 2; b++) acc[a][b] = (f32x4){0.f, 0.f, 0.f, 0.f};

#define DN_GLA(B, K0) {                                                        \
    _Pragma("unroll") for (int j = 0; j < 4; j++)                              \
      gload16(srcA[j] + (K0), &lA[B][dstAo[j]]); }

#define DN_LOADB(K0) {                                                         \
    _Pragma("unroll") for (int i = 0; i < 4; i++)                              \
      vb[i] = *(const f32x4*)(pB + (K0) + i * 4); }

#define DN_CVTW() {                                                            \
    u32x4 w0 = { pk2(vb[0][0], vb[0][1]), pk2(vb[0][2], vb[0][3]),             \
                 pk2(vb[1][0], vb[1][1]), pk2(vb[1][2], vb[1][3]) };           \
    *(u32x4*)&lB[bws0] = w0;                                                   \
    u32x4 w1 = { pk2(vb[2][0], vb[2][1]), pk2(vb[2][2], vb[2][3]),             \
                 pk2(vb[3][0], vb[3][1]), pk2(vb[3][2], vb[3][3]) };           \
    *(u32x4*)&lB[bws1] = w1; }

#define DN_COMP(B) {                                                           \
    _Pragma("unroll") for (int kk2 = 0; kk2 < 2; kk2++) {                      \
      bf16x8 af[4], bf[2];                                                     \
      _Pragma("unroll") for (int m2 = 0; m2 < 4; m2++) {                       \
        int r = wm * 64 + m2 * 16 + fr, q = kk2 * 4 + fq;                      \
        af[m2] = *(const bf16x8*)&lA[B][r * 64 + (q ^ (r & 7)) * 8];           \
      }                                                                        \
      _Pragma("unroll") for (int n2 = 0; n2 < 2; n2++) {                       \
        int r = wn * 32 + n2 * 16 + fr, q = kk2 * 4 + fq;                      \
        bf[n2] = *(const bf16x8*)&lB[r * 64 + (q ^ (r & 7)) * 8];              \
      }                                                                        \
      _Pragma("unroll") for (int m2 = 0; m2 < 4; m2++)                         \
        _Pragma("unroll") for (int n2 = 0; n2 < 2; n2++)                       \
          acc[m2][n2] = mfma_bf16(af[m2], bf[n2], acc[m2][n2]);                \
    } }

  DN_GLA(0, 0);
  DN_LOADB(0);
  for (int t = 0; t < 16; ++t) {
    const int c = t & 1;
    DN_CVTW();
    if (t < 15) {
      DN_GLA(c ^ 1, (t + 1) * 64);
      DN_LOADB((t + 1) * 64);
    }
    BAR();
    DN_COMP(c);
    BAR();
  }
#undef DN_GLA
#undef DN_LOADB
#undef DN_CVTW
#undef DN_COMP

  // epilogue: out[token] += w * val
  #pragma unroll
  for (int m2 = 0; m2 < 4; m2++)
    #pragma unroll
    for (int q = 0; q < 4; q++) {
      int row = m0 + wm * 64 + m2 * 16 + fq * 4 + q;
      int p = perm[row];
      if (p < 0) continue;
      int t = p >> 1;
      float w = rw[p];
      #pragma unroll
      for (int n2 = 0; n2 < 2; n2++) {
        int col = n0 + wn * 32 + n2 * 16 + fr;
        atomicAdd(&out[(size_t)t * HID + col], acc[m2][n2][q] * w);
      }
    }
}

extern "C" void kernel_launch(void* const* d_in, const int* in_sizes, int n_in,
                              void* d_out, int out_size, void* d_ws, size_t ws_size,
                              hipStream_t stream) {
  const float* x   = (const float*)d_in[0];
  const float* rw  = (const float*)d_in[1];
  const int*   sel = (const int*)d_in[2];
  const float* gw  = (const float*)d_in[4];
  const float* uw  = (const float*)d_in[5];
  const float* dw  = (const float*)d_in[6];
  float* out = (float*)d_out;

  char* ws = (char*)d_ws;
  int*  hdr  = (int*)ws;                          // seg_base[9]
  int*  perm = (int*)(ws + 1024);                 // PERM_MAX ints
  u16*  xb   = (u16*)(ws + (1 << 16));            // 2M bf16 = 4 MiB
  u16*  hbuf = xb + (2 << 20);                    // 5120*1024 bf16 = 10 MiB

  k_prep <<<dim3(1024), dim3(256), 0, stream>>>(x, xb, out);
  k_route<<<dim3(1),    dim3(256), 0, stream>>>(sel, hdr, perm);
  k_gateup<<<dim3(16, MT_MAX), dim3(256), 0, stream>>>(xb, gw, uw, hdr, perm, hbuf);
  k_down  <<<dim3(16, MT_MAX), dim3(256), 0, stream>>>(hbuf, dw, hdr, perm, rw, out);
}